// Round 5
// baseline (608.971 us; speedup 1.0000x reference)
//
#include <hip/hip_runtime.h>
#include <hip/hip_bf16.h>
#include <stdint.h>

#define N_NODES 100000
#define N_EDGES 1600000
#define DIM 128
#define N_GRAPHS 128
#define LDA 136   // padded LDS stride in bf16 elems (k_layer)

#define NBKT 196     // buckets of 512 nodes: bucket = dst >> 9
#define BCAP 12288   // per-bucket temp capacity (mean 8163, sigma ~90)
#define BP   10240   // per-bucket padded colx capacity (mult of 4; max padded ~10061)

typedef unsigned int uint32;
typedef unsigned short ushort16;

typedef __bf16 bf16x8 __attribute__((ext_vector_type(8)));
typedef float fx4 __attribute__((ext_vector_type(4)));

__device__ __forceinline__ float bfLo(uint32 u){ return __builtin_bit_cast(float, (uint32)(u << 16)); }
__device__ __forceinline__ float bfHi(uint32 u){ return __builtin_bit_cast(float, (uint32)(u & 0xFFFF0000u)); }
__device__ __forceinline__ ushort16 f2bf(float f){
  uint32 u = __builtin_bit_cast(uint32, f);
  u = u + 0x7FFFu + ((u >> 16) & 1u);   // round-to-nearest-even
  return (ushort16)(u >> 16);
}
__device__ __forceinline__ uint32 pack2(float a, float b){
  return (uint32)f2bf(a) | ((uint32)f2bf(b) << 16);
}

// ---------- prep: cvt x -> bf16, zero pad rows + bucketCursor, transpose W -> bf16 ----------
__global__ __launch_bounds__(256) void k_prep(const float* __restrict__ x,
                                              ushort16* __restrict__ P, ushort16* __restrict__ Q,
                                              const float* __restrict__ W1, const float* __restrict__ W2,
                                              ushort16* __restrict__ WtA, ushort16* __restrict__ WtB,
                                              int* __restrict__ bucketCursor){
  int b = blockIdx.x;
  int t = threadIdx.x;
  if (b < 6250){
    int idx = (b*256 + t) * 8;   // 6250*256*8 = 12.8M exactly
    float4 v0 = *(const float4*)(x + idx);
    float4 v1 = *(const float4*)(x + idx + 4);
    uint4 o;
    o.x = pack2(v0.x, v0.y); o.y = pack2(v0.z, v0.w);
    o.z = pack2(v1.x, v1.y); o.w = pack2(v1.z, v1.w);
    *(uint4*)(P + idx) = o;
  } else if (b == 6250){
    uint4 z = {0u,0u,0u,0u};
    if (t < 16)       *(uint4*)(P + (size_t)N_NODES*128 + t*8)      = z;
    else if (t < 32)  *(uint4*)(Q + (size_t)N_NODES*128 + (t-16)*8) = z;
    if (t < NBKT + 1) bucketCursor[t] = 0;
  } else {
    int idx = (b - 6251)*256 + t;   // 0..98303
    const float* src = (idx < 49152) ? W1 : W2;
    ushort16*    dst = (idx < 49152) ? WtA : WtB;
    int il = idx % 49152;
    int layer = il >> 14;
    int n = (il >> 7) & 127;
    int k = il & 127;
    dst[layer*16384 + n*128 + k] = f2bf(src[layer*16384 + k*128 + n]);
  }
}

// ---------- CSR build: two-phase LDS counting sort ----------
__global__ __launch_bounds__(512) void k_binA(const int* __restrict__ ei,
                                              int* __restrict__ bucketCursor,
                                              int* __restrict__ temp){
  __shared__ int hist[NBKT];
  __shared__ int base[NBKT];
  __shared__ int gbase[NBKT];
  __shared__ int scanbuf[256];
  __shared__ int sVal[8192];
  __shared__ unsigned short sBkt[8192];
  int t = threadIdx.x;
  int e0 = blockIdx.x * 8192;

  for (int i = t; i < NBKT; i += 512) hist[i] = 0;
  __syncthreads();

  int   myv[16];
  short myb[16];
  short myr[16];
  #pragma unroll
  for (int it = 0; it < 16; ++it){
    int e = e0 + it*512 + t;
    int v = 0; short b = -1; short r = 0;
    if (e < N_EDGES){
      int s = ei[e];
      int d = ei[N_EDGES + e];
      b = (short)(d >> 9);
      v = s | ((d & 511) << 17);
      r = (short)atomicAdd(&hist[b], 1);
    }
    myv[it] = v; myb[it] = b; myr[it] = r;
  }
  __syncthreads();

  if (t < 256) scanbuf[t] = (t < NBKT) ? hist[t] : 0;
  __syncthreads();
  for (int off = 1; off < 256; off <<= 1){
    int x = 0;
    if (t < 256 && t >= off) x = scanbuf[t - off];
    __syncthreads();
    if (t < 256) scanbuf[t] += x;
    __syncthreads();
  }
  if (t < NBKT){
    base[t]  = scanbuf[t] - hist[t];                 // exclusive
    gbase[t] = atomicAdd(&bucketCursor[t], hist[t]); // reserve run
  }
  __syncthreads();

  #pragma unroll
  for (int it = 0; it < 16; ++it){
    if (myb[it] >= 0){
      int p = base[myb[it]] + myr[it];
      sVal[p] = myv[it];
      sBkt[p] = (unsigned short)myb[it];
    }
  }
  __syncthreads();

  int cnt = scanbuf[NBKT - 1];
  for (int p = t; p < cnt; p += 512){
    int b = sBkt[p];
    int g = gbase[b] + (p - base[b]);
    if (g < BCAP) temp[b*BCAP + g] = sVal[p];
  }
}

// Phase B: one block per bucket; build 512-node sub-CSR in LDS with per-node
// padding to multiple-of-4 (pad slots -> zero row N_NODES); coalesced colx write.
__global__ __launch_bounds__(512) void k_binB(const int* __restrict__ temp,
                                              const int* __restrict__ bucketCursor,
                                              int* __restrict__ rowptr,
                                              int* __restrict__ rowlen,
                                              int* __restrict__ colx){
  __shared__ int counts[512];
  __shared__ int sc[512];
  __shared__ int cur[512];
  __shared__ int stage[BCAP];
  __shared__ int sorted[BCAP];
  int b = blockIdx.x, t = threadIdx.x;
  int cnt = min(bucketCursor[b], BCAP);
  int gb  = b * BP;
  const int* src = temp + b*BCAP;

  counts[t] = 0;
  __syncthreads();
  for (int p = t; p < cnt; p += 512){
    int v = src[p];
    stage[p] = v;
    atomicAdd(&counts[v >> 17], 1);
  }
  __syncthreads();

  int len  = counts[t];
  int plen = (len + 3) & ~3;          // padded to multiple of 4
  sc[t] = plen; __syncthreads();
  for (int off = 1; off < 512; off <<= 1){
    int x = (t >= off) ? sc[t - off] : 0; __syncthreads(); sc[t] += x; __syncthreads();
  }
  int excl = sc[t] - plen;
  cur[t] = excl;
  int node = b*512 + t;
  if (node < N_NODES){ rowptr[node] = gb + excl; rowlen[node] = plen; }
  __syncthreads();

  for (int p = t; p < cnt; p += 512){
    int v = stage[p];
    int d = v >> 17;
    int pos = atomicAdd(&cur[d], 1);
    sorted[pos] = v & 0x1FFFF;
  }
  __syncthreads();

  for (int k = len; k < plen; ++k) sorted[excl + k] = N_NODES;
  __syncthreads();

  int total = sc[511];
  for (int p = t; p < total; p += 512) colx[gb + p] = sorted[p];
}

// ---------- fused layer: agg (CSR gather) + GIN MLP, reads xb only, writes ob rows it owns ----------
// Gather: wave handles 16 nodes; lane (g=lane>>4,o=lane&15) loads 16B of row colx[j+g]
// (one dwordx4 = 4 rows), shfl-reduce over g, add own x row, stage to sA.
// Then: h=relu((x+agg)@W1+b1); out=h@W2+b2 via 16x16x32 bf16 MFMA.
__global__ __launch_bounds__(256) void k_layer(const ushort16* __restrict__ xb, ushort16* __restrict__ ob,
                                               const int* __restrict__ rowptr, const int* __restrict__ rowlen,
                                               const int* __restrict__ colx,
                                               const ushort16* __restrict__ Wt1, const float* __restrict__ b1,
                                               const ushort16* __restrict__ Wt2, const float* __restrict__ b2){
  __shared__ __attribute__((aligned(16))) ushort16 sA[64 * LDA];
  __shared__ __attribute__((aligned(16))) ushort16 sW[128 * LDA];
  int t = threadIdx.x;
  int row0 = blockIdx.x * 64;
  int wave = t >> 6, lane = t & 63, g = lane >> 4, o = lane & 15;

  // stage sW = W1^T (all 256 threads, 8 rows each)
  {
    int sr = t >> 4;           // 0..15
    int scc = (t & 15) * 8;
    #pragma unroll
    for (int it = 0; it < 8; ++it){
      int row = it*16 + sr;
      *(uint4*)(sW + row*LDA + scc) = *(const uint4*)(Wt1 + row*128 + scc);
    }
  }

  const uint32* xw = (const uint32*)xb;

  // gather phase: wave's 16 nodes
  for (int i = 0; i < 16; ++i){
    int node = row0 + wave*16 + i;
    float f0=0.f,f1=0.f,f2=0.f,f3=0.f,f4=0.f,f5=0.f,f6=0.f,f7=0.f;
    if (node < N_NODES){
      int j   = rowptr[node];
      int end = j + rowlen[node];
      while (j + 8 <= end){
        int4 c0 = *(const int4*)(colx + j);
        int4 c1 = *(const int4*)(colx + j + 4);
        int r0ab = (g & 1) ? c0.y : c0.x;
        int r0cd = (g & 1) ? c0.w : c0.z;
        int r0   = (g & 2) ? r0cd : r0ab;
        int r1ab = (g & 1) ? c1.y : c1.x;
        int r1cd = (g & 1) ? c1.w : c1.z;
        int r1   = (g & 2) ? r1cd : r1ab;
        uint4 u0 = *(const uint4*)(xw + (size_t)r0*64 + o*4);
        uint4 u1 = *(const uint4*)(xw + (size_t)r1*64 + o*4);
        f0 += bfLo(u0.x); f1 += bfHi(u0.x); f2 += bfLo(u0.y); f3 += bfHi(u0.y);
        f4 += bfLo(u0.z); f5 += bfHi(u0.z); f6 += bfLo(u0.w); f7 += bfHi(u0.w);
        f0 += bfLo(u1.x); f1 += bfHi(u1.x); f2 += bfLo(u1.y); f3 += bfHi(u1.y);
        f4 += bfLo(u1.z); f5 += bfHi(u1.z); f6 += bfLo(u1.w); f7 += bfHi(u1.w);
        j += 8;
      }
      if (j < end){
        int4 c0 = *(const int4*)(colx + j);
        int rab = (g & 1) ? c0.y : c0.x;
        int rcd = (g & 1) ? c0.w : c0.z;
        int r0  = (g & 2) ? rcd : rab;
        uint4 u0 = *(const uint4*)(xw + (size_t)r0*64 + o*4);
        f0 += bfLo(u0.x); f1 += bfHi(u0.x); f2 += bfLo(u0.y); f3 += bfHi(u0.y);
        f4 += bfLo(u0.z); f5 += bfHi(u0.z); f6 += bfLo(u0.w); f7 += bfHi(u0.w);
      }
    }
    // reduce over edge-slot groups (lane bits 4,5)
    f0 += __shfl_xor(f0, 16, 64); f1 += __shfl_xor(f1, 16, 64);
    f2 += __shfl_xor(f2, 16, 64); f3 += __shfl_xor(f3, 16, 64);
    f4 += __shfl_xor(f4, 16, 64); f5 += __shfl_xor(f5, 16, 64);
    f6 += __shfl_xor(f6, 16, 64); f7 += __shfl_xor(f7, 16, 64);
    f0 += __shfl_xor(f0, 32, 64); f1 += __shfl_xor(f1, 32, 64);
    f2 += __shfl_xor(f2, 32, 64); f3 += __shfl_xor(f3, 32, 64);
    f4 += __shfl_xor(f4, 32, 64); f5 += __shfl_xor(f5, 32, 64);
    f6 += __shfl_xor(f6, 32, 64); f7 += __shfl_xor(f7, 32, 64);

    if (g == 0){
      uint4 r = {0u,0u,0u,0u};
      if (node < N_NODES){
        uint4 xv = *(const uint4*)(xw + (size_t)node*64 + o*4);
        r.x = pack2(f0 + bfLo(xv.x), f1 + bfHi(xv.x));
        r.y = pack2(f2 + bfLo(xv.y), f3 + bfHi(xv.y));
        r.z = pack2(f4 + bfLo(xv.z), f5 + bfHi(xv.z));
        r.w = pack2(f6 + bfLo(xv.w), f7 + bfHi(xv.w));
      }
      *(uint4*)(sA + (wave*16 + i)*LDA + o*8) = r;
    }
  }
  __syncthreads();

  int m = lane & 15, kg = lane >> 4;
  fx4 acc[8];
  #pragma unroll
  for (int nt = 0; nt < 8; ++nt) acc[nt] = (fx4){0.f,0.f,0.f,0.f};

  const ushort16* aBase = sA + (wave*16 + m)*LDA + kg*8;
  const ushort16* bBase = sW + m*LDA + kg*8;

  // GEMM1
  #pragma unroll
  for (int kt = 0; kt < 4; ++kt){
    bf16x8 av = *(const bf16x8*)(aBase + kt*32);
    #pragma unroll
    for (int nt = 0; nt < 8; ++nt){
      bf16x8 bv = *(const bf16x8*)(bBase + nt*16*LDA + kt*32);
      acc[nt] = __builtin_amdgcn_mfma_f32_16x16x32_bf16(av, bv, acc[nt], 0, 0, 0);
    }
  }
  __syncthreads();

  // h = relu(acc + b1) -> sA (C-layout: col = m + 16*nt, row = kg*4 + r)
  #pragma unroll
  for (int nt = 0; nt < 8; ++nt){
    float bv = b1[nt*16 + m];
    #pragma unroll
    for (int r = 0; r < 4; ++r){
      float v = acc[nt][r] + bv;
      v = fmaxf(v, 0.f);
      sA[(wave*16 + kg*4 + r)*LDA + nt*16 + m] = f2bf(v);
    }
  }
  // stage sW = W2^T
  {
    int sr = t >> 4;
    int scc = (t & 15) * 8;
    #pragma unroll
    for (int it = 0; it < 8; ++it){
      int row = it*16 + sr;
      *(uint4*)(sW + row*LDA + scc) = *(const uint4*)(Wt2 + row*128 + scc);
    }
  }
  __syncthreads();

  #pragma unroll
  for (int nt = 0; nt < 8; ++nt) acc[nt] = (fx4){0.f,0.f,0.f,0.f};

  // GEMM2
  #pragma unroll
  for (int kt = 0; kt < 4; ++kt){
    bf16x8 av = *(const bf16x8*)(aBase + kt*32);
    #pragma unroll
    for (int nt = 0; nt < 8; ++nt){
      bf16x8 bv = *(const bf16x8*)(bBase + nt*16*LDA + kt*32);
      acc[nt] = __builtin_amdgcn_mfma_f32_16x16x32_bf16(av, bv, acc[nt], 0, 0, 0);
    }
  }

  // epilogue: out = acc + b2 -> ob (bf16), only rows this block owns (ping-pong safe)
  #pragma unroll
  for (int nt = 0; nt < 8; ++nt){
    float bv = b2[nt*16 + m];
    #pragma unroll
    for (int r = 0; r < 4; ++r){
      int gnode = row0 + wave*16 + kg*4 + r;
      if (gnode < N_NODES){
        float v = acc[nt][r] + bv;
        ob[(size_t)gnode*128 + nt*16 + m] = f2bf(v);
      }
    }
  }
}

// ---------- sum-pool per graph (batch sorted), atomic-free: one block per graph ----------
__device__ __forceinline__ int lower_bound_i(const int* __restrict__ a, int n, int key){
  int lo = 0, hi = n;
  while (lo < hi){ int mid = (lo + hi) >> 1; if (a[mid] < key) lo = mid + 1; else hi = mid; }
  return lo;
}

__global__ __launch_bounds__(1024) void k_pool(const ushort16* __restrict__ xb, const int* __restrict__ batch,
                                               float* __restrict__ out){
  int g = blockIdx.x;
  int start = lower_bound_i(batch, N_NODES, g);
  int end   = lower_bound_i(batch, N_NODES, g + 1);
  int t = threadIdx.x;
  int c = t & 127;
  int h = t >> 7;   // 0..7
  float acc = 0.f;
  for (int r = start + h; r < end; r += 8){
    uint32 u = (uint32)xb[(size_t)r*128 + c];
    acc += __builtin_bit_cast(float, (uint32)(u << 16));
  }
  __shared__ float red[1024];
  red[t] = acc; __syncthreads();
  if (t < 512) red[t] += red[t + 512];
  __syncthreads();
  if (t < 256) red[t] += red[t + 256];
  __syncthreads();
  if (t < 128) out[(size_t)g*128 + c] = red[t] + red[t + 128];
}

// ---------- launch ----------
extern "C" void kernel_launch(void* const* d_in, const int* in_sizes, int n_in,
                              void* d_out, int out_size, void* d_ws, size_t ws_size,
                              hipStream_t stream) {
  const float* x   = (const float*)d_in[0];
  const float* W1  = (const float*)d_in[1];
  const float* b1  = (const float*)d_in[2];
  const float* W2  = (const float*)d_in[3];
  const float* b2  = (const float*)d_in[4];
  const int*   ei  = (const int*)d_in[5];
  const int*   bat = (const int*)d_in[6];
  float* out = (float*)d_out;

  char* w = (char*)d_ws;
  auto carve = [&](size_t bytes) -> char* {
    char* p = w; w += (bytes + 255) & ~(size_t)255; return p;
  };
  ushort16* P    = (ushort16*)carve((size_t)(N_NODES+1) * DIM * 2);  // +1: zero pad row
  ushort16* Q    = (ushort16*)carve((size_t)(N_NODES+1) * DIM * 2);
  ushort16* WtA  = (ushort16*)carve(3 * 16384 * 2);
  ushort16* WtB  = (ushort16*)carve(3 * 16384 * 2);
  int* rowptr    = (int*)carve((size_t)N_NODES * 4);
  int* rowlen    = (int*)carve((size_t)N_NODES * 4);
  int* colx      = (int*)carve((size_t)NBKT * BP * 4);   // 8.03 MB, fixed bucket regions
  int* bucketCursor = (int*)carve((NBKT + 1) * 4);
  // temp bucket regions alias Q: only live during CSR build (first 9.63 MB; Q pad row at 25.6 MB is safe)
  int* temp      = (int*)Q;

  // 7 dispatches total, no memsets (bucketCursor zeroed in k_prep; pool writes directly)
  k_prep<<<6635, 256, 0, stream>>>(x, P, Q, W1, W2, WtA, WtB, bucketCursor);
  k_binA<<<(N_EDGES + 8191)/8192, 512, 0, stream>>>(ei, bucketCursor, temp);
  k_binB<<<NBKT, 512, 0, stream>>>(temp, bucketCursor, rowptr, rowlen, colx);

  const int layerGrid = (N_NODES + 63) / 64;  // 1563

  // layer 0: read P, write Q
  k_layer<<<layerGrid, 256, 0, stream>>>(P, Q, rowptr, rowlen, colx,
                                         WtA + 0*16384, b1 + 0*128, WtB + 0*16384, b2 + 0*128);
  // layer 1: read Q, write P
  k_layer<<<layerGrid, 256, 0, stream>>>(Q, P, rowptr, rowlen, colx,
                                         WtA + 1*16384, b1 + 1*128, WtB + 1*16384, b2 + 1*128);
  // layer 2: read P, write Q
  k_layer<<<layerGrid, 256, 0, stream>>>(P, Q, rowptr, rowlen, colx,
                                         WtA + 2*16384, b1 + 2*128, WtB + 2*16384, b2 + 2*128);

  k_pool<<<N_GRAPHS, 1024, 0, stream>>>(Q, bat, out);
}

// Round 6
// 475.593 us; speedup vs baseline: 1.2804x; 1.2804x over previous
//
#include <hip/hip_runtime.h>
#include <hip/hip_bf16.h>
#include <stdint.h>

#define N_NODES 100000
#define N_EDGES 1600000
#define DIM 128
#define N_GRAPHS 128
#define LDA 136   // padded LDS stride in bf16 elems (k_mlp)

#define NBKT 196     // buckets of 512 nodes: bucket = dst >> 9
#define BCAP 12288   // per-bucket temp capacity (mean 8163, sigma ~90)
#define BP   10240   // per-bucket padded colx capacity (mult of 4; max padded ~10061)

typedef unsigned int uint32;
typedef unsigned short ushort16;

typedef __bf16 bf16x8 __attribute__((ext_vector_type(8)));
typedef float fx4 __attribute__((ext_vector_type(4)));

__device__ __forceinline__ float bfLo(uint32 u){ return __builtin_bit_cast(float, (uint32)(u << 16)); }
__device__ __forceinline__ float bfHi(uint32 u){ return __builtin_bit_cast(float, (uint32)(u & 0xFFFF0000u)); }
__device__ __forceinline__ ushort16 f2bf(float f){
  uint32 u = __builtin_bit_cast(uint32, f);
  u = u + 0x7FFFu + ((u >> 16) & 1u);   // round-to-nearest-even
  return (ushort16)(u >> 16);
}
__device__ __forceinline__ uint32 pack2(float a, float b){
  return (uint32)f2bf(a) | ((uint32)f2bf(b) << 16);
}

// ---------- prep: cvt x -> bf16, zero pad rows + bucketCursor, transpose W -> bf16 ----------
__global__ __launch_bounds__(256) void k_prep(const float* __restrict__ x,
                                              ushort16* __restrict__ P, ushort16* __restrict__ Q,
                                              const float* __restrict__ W1, const float* __restrict__ W2,
                                              ushort16* __restrict__ WtA, ushort16* __restrict__ WtB,
                                              int* __restrict__ bucketCursor){
  int b = blockIdx.x;
  int t = threadIdx.x;
  if (b < 6250){
    int idx = (b*256 + t) * 8;   // 6250*256*8 = 12.8M exactly
    float4 v0 = *(const float4*)(x + idx);
    float4 v1 = *(const float4*)(x + idx + 4);
    uint4 o;
    o.x = pack2(v0.x, v0.y); o.y = pack2(v0.z, v0.w);
    o.z = pack2(v1.x, v1.y); o.w = pack2(v1.z, v1.w);
    *(uint4*)(P + idx) = o;
  } else if (b == 6250){
    uint4 z = {0u,0u,0u,0u};
    if (t < 16)       *(uint4*)(P + (size_t)N_NODES*128 + t*8)      = z;
    else if (t < 32)  *(uint4*)(Q + (size_t)N_NODES*128 + (t-16)*8) = z;
    if (t < NBKT + 1) bucketCursor[t] = 0;
  } else {
    int idx = (b - 6251)*256 + t;   // 0..98303
    const float* src = (idx < 49152) ? W1 : W2;
    ushort16*    dst = (idx < 49152) ? WtA : WtB;
    int il = idx % 49152;
    int layer = il >> 14;
    int n = (il >> 7) & 127;
    int k = il & 127;
    dst[layer*16384 + n*128 + k] = f2bf(src[layer*16384 + k*128 + n]);
  }
}

// ---------- CSR build: two-phase LDS counting sort ----------
__global__ __launch_bounds__(512) void k_binA(const int* __restrict__ ei,
                                              int* __restrict__ bucketCursor,
                                              int* __restrict__ temp){
  __shared__ int hist[NBKT];
  __shared__ int base[NBKT];
  __shared__ int gbase[NBKT];
  __shared__ int scanbuf[256];
  __shared__ int sVal[8192];
  __shared__ unsigned short sBkt[8192];
  int t = threadIdx.x;
  int e0 = blockIdx.x * 8192;

  for (int i = t; i < NBKT; i += 512) hist[i] = 0;
  __syncthreads();

  int   myv[16];
  short myb[16];
  short myr[16];
  #pragma unroll
  for (int it = 0; it < 16; ++it){
    int e = e0 + it*512 + t;
    int v = 0; short b = -1; short r = 0;
    if (e < N_EDGES){
      int s = ei[e];
      int d = ei[N_EDGES + e];
      b = (short)(d >> 9);
      v = s | ((d & 511) << 17);
      r = (short)atomicAdd(&hist[b], 1);
    }
    myv[it] = v; myb[it] = b; myr[it] = r;
  }
  __syncthreads();

  if (t < 256) scanbuf[t] = (t < NBKT) ? hist[t] : 0;
  __syncthreads();
  for (int off = 1; off < 256; off <<= 1){
    int x = 0;
    if (t < 256 && t >= off) x = scanbuf[t - off];
    __syncthreads();
    if (t < 256) scanbuf[t] += x;
    __syncthreads();
  }
  if (t < NBKT){
    base[t]  = scanbuf[t] - hist[t];                 // exclusive
    gbase[t] = atomicAdd(&bucketCursor[t], hist[t]); // reserve run
  }
  __syncthreads();

  #pragma unroll
  for (int it = 0; it < 16; ++it){
    if (myb[it] >= 0){
      int p = base[myb[it]] + myr[it];
      sVal[p] = myv[it];
      sBkt[p] = (unsigned short)myb[it];
    }
  }
  __syncthreads();

  int cnt = scanbuf[NBKT - 1];
  for (int p = t; p < cnt; p += 512){
    int b = sBkt[p];
    int g = gbase[b] + (p - base[b]);
    if (g < BCAP) temp[b*BCAP + g] = sVal[p];
  }
}

// Phase B: one block per bucket; build 512-node sub-CSR in LDS with per-node
// padding to multiple-of-4 (pad slots -> zero row N_NODES); coalesced colx write.
// Emits rowmeta[node] = {start, paddedLen} as int2 (one load in k_agg).
__global__ __launch_bounds__(512) void k_binB(const int* __restrict__ temp,
                                              const int* __restrict__ bucketCursor,
                                              int2* __restrict__ rowmeta,
                                              int* __restrict__ colx){
  __shared__ int counts[512];
  __shared__ int sc[512];
  __shared__ int cur[512];
  __shared__ int stage[BCAP];
  __shared__ int sorted[BCAP];
  int b = blockIdx.x, t = threadIdx.x;
  int cnt = min(bucketCursor[b], BCAP);
  int gb  = b * BP;
  const int* src = temp + b*BCAP;

  counts[t] = 0;
  __syncthreads();
  for (int p = t; p < cnt; p += 512){
    int v = src[p];
    stage[p] = v;
    atomicAdd(&counts[v >> 17], 1);
  }
  __syncthreads();

  int len  = counts[t];
  int plen = (len + 3) & ~3;          // padded to multiple of 4
  sc[t] = plen; __syncthreads();
  for (int off = 1; off < 512; off <<= 1){
    int x = (t >= off) ? sc[t - off] : 0; __syncthreads(); sc[t] += x; __syncthreads();
  }
  int excl = sc[t] - plen;
  cur[t] = excl;
  int node = b*512 + t;
  if (node < N_NODES) rowmeta[node] = make_int2(gb + excl, plen);
  __syncthreads();

  for (int p = t; p < cnt; p += 512){
    int v = stage[p];
    int d = v >> 17;
    int pos = atomicAdd(&cur[d], 1);
    sorted[pos] = v & 0x1FFFF;
  }
  __syncthreads();

  for (int k = len; k < plen; ++k) sorted[excl + k] = N_NODES;
  __syncthreads();

  int total = sc[511];
  for (int p = t; p < total; p += 512) colx[gb + p] = sorted[p];
}

// ---------- aggregation: one wave per TWO adjacent nodes, dwordx4 gather (4 rows/instr) ----------
// Writes h0 = x + agg (GIN eps=0) so k_mlp reads a single buffer.
// lane (g=lane>>4, o=lane&15): loads bytes [o*16, o*16+16) of row colx[j+g].
__device__ __forceinline__ int sel_g(int4 c, int g){
  int ab = (g & 1) ? c.y : c.x;
  int cd = (g & 1) ? c.w : c.z;
  return (g & 2) ? cd : ab;
}

__global__ __launch_bounds__(1024) void k_agg(const ushort16* __restrict__ xb, ushort16* __restrict__ ob,
                                              const int2* __restrict__ rowmeta, const int* __restrict__ colx){
  int w = (blockIdx.x*1024 + threadIdx.x) >> 6;   // 3125 blocks * 16 waves = 50000
  int lane = threadIdx.x & 63;
  int g = lane >> 4, o = lane & 15;
  int nA = 2*w, nB = 2*w + 1;
  int4 meta = *(const int4*)(rowmeta + nA);       // {startA, lenA, startB, lenB}, 16B aligned
  int ja = meta.x, ea = meta.x + meta.y;
  int jb = meta.z, eb = meta.z + meta.w;
  const uint32* xw = (const uint32*)xb;

  // prefetch self rows early (independent of the gather chain)
  uint4 selfA = *(const uint4*)(xw + (size_t)nA*64 + o*4);
  uint4 selfB = *(const uint4*)(xw + (size_t)nB*64 + o*4);

  float a0=0.f,a1=0.f,a2=0.f,a3=0.f,a4=0.f,a5=0.f,a6=0.f,a7=0.f;
  float b0=0.f,b1=0.f,b2=0.f,b3=0.f,b4=0.f,b5=0.f,b6=0.f,b7=0.f;

  // joint loop: 8 edges per node -> 4 colx int4 + 4 row dwordx4 in flight, 2 indep chains
  while (ja + 8 <= ea && jb + 8 <= eb){
    int4 cA0 = *(const int4*)(colx + ja);
    int4 cA1 = *(const int4*)(colx + ja + 4);
    int4 cB0 = *(const int4*)(colx + jb);
    int4 cB1 = *(const int4*)(colx + jb + 4);
    int rA0 = sel_g(cA0, g), rA1 = sel_g(cA1, g);
    int rB0 = sel_g(cB0, g), rB1 = sel_g(cB1, g);
    uint4 uA0 = *(const uint4*)(xw + (size_t)rA0*64 + o*4);
    uint4 uA1 = *(const uint4*)(xw + (size_t)rA1*64 + o*4);
    uint4 uB0 = *(const uint4*)(xw + (size_t)rB0*64 + o*4);
    uint4 uB1 = *(const uint4*)(xw + (size_t)rB1*64 + o*4);
    a0 += bfLo(uA0.x) + bfLo(uA1.x); a1 += bfHi(uA0.x) + bfHi(uA1.x);
    a2 += bfLo(uA0.y) + bfLo(uA1.y); a3 += bfHi(uA0.y) + bfHi(uA1.y);
    a4 += bfLo(uA0.z) + bfLo(uA1.z); a5 += bfHi(uA0.z) + bfHi(uA1.z);
    a6 += bfLo(uA0.w) + bfLo(uA1.w); a7 += bfHi(uA0.w) + bfHi(uA1.w);
    b0 += bfLo(uB0.x) + bfLo(uB1.x); b1 += bfHi(uB0.x) + bfHi(uB1.x);
    b2 += bfLo(uB0.y) + bfLo(uB1.y); b3 += bfHi(uB0.y) + bfHi(uB1.y);
    b4 += bfLo(uB0.z) + bfLo(uB1.z); b5 += bfHi(uB0.z) + bfHi(uB1.z);
    b6 += bfLo(uB0.w) + bfLo(uB1.w); b7 += bfHi(uB0.w) + bfHi(uB1.w);
    ja += 8; jb += 8;
  }
  // node A remainder (lists padded to mult of 4 -> chunks of 8 then possibly one 4)
  for (; ja + 8 <= ea; ja += 8){
    int4 c0 = *(const int4*)(colx + ja);
    int4 c1 = *(const int4*)(colx + ja + 4);
    int r0 = sel_g(c0, g), r1 = sel_g(c1, g);
    uint4 u0 = *(const uint4*)(xw + (size_t)r0*64 + o*4);
    uint4 u1 = *(const uint4*)(xw + (size_t)r1*64 + o*4);
    a0 += bfLo(u0.x) + bfLo(u1.x); a1 += bfHi(u0.x) + bfHi(u1.x);
    a2 += bfLo(u0.y) + bfLo(u1.y); a3 += bfHi(u0.y) + bfHi(u1.y);
    a4 += bfLo(u0.z) + bfLo(u1.z); a5 += bfHi(u0.z) + bfHi(u1.z);
    a6 += bfLo(u0.w) + bfLo(u1.w); a7 += bfHi(u0.w) + bfHi(u1.w);
  }
  if (ja < ea){
    int4 c0 = *(const int4*)(colx + ja);
    int r0 = sel_g(c0, g);
    uint4 u0 = *(const uint4*)(xw + (size_t)r0*64 + o*4);
    a0 += bfLo(u0.x); a1 += bfHi(u0.x); a2 += bfLo(u0.y); a3 += bfHi(u0.y);
    a4 += bfLo(u0.z); a5 += bfHi(u0.z); a6 += bfLo(u0.w); a7 += bfHi(u0.w);
  }
  // node B remainder
  for (; jb + 8 <= eb; jb += 8){
    int4 c0 = *(const int4*)(colx + jb);
    int4 c1 = *(const int4*)(colx + jb + 4);
    int r0 = sel_g(c0, g), r1 = sel_g(c1, g);
    uint4 u0 = *(const uint4*)(xw + (size_t)r0*64 + o*4);
    uint4 u1 = *(const uint4*)(xw + (size_t)r1*64 + o*4);
    b0 += bfLo(u0.x) + bfLo(u1.x); b1 += bfHi(u0.x) + bfHi(u1.x);
    b2 += bfLo(u0.y) + bfLo(u1.y); b3 += bfHi(u0.y) + bfHi(u1.y);
    b4 += bfLo(u0.z) + bfLo(u1.z); b5 += bfHi(u0.z) + bfHi(u1.z);
    b6 += bfLo(u0.w) + bfLo(u1.w); b7 += bfHi(u0.w) + bfHi(u1.w);
  }
  if (jb < eb){
    int4 c0 = *(const int4*)(colx + jb);
    int r0 = sel_g(c0, g);
    uint4 u0 = *(const uint4*)(xw + (size_t)r0*64 + o*4);
    b0 += bfLo(u0.x); b1 += bfHi(u0.x); b2 += bfLo(u0.y); b3 += bfHi(u0.y);
    b4 += bfLo(u0.z); b5 += bfHi(u0.z); b6 += bfLo(u0.w); b7 += bfHi(u0.w);
  }

  // reduce over edge-slot groups (lane bits 4,5)
  a0 += __shfl_xor(a0, 16, 64); a1 += __shfl_xor(a1, 16, 64);
  a2 += __shfl_xor(a2, 16, 64); a3 += __shfl_xor(a3, 16, 64);
  a4 += __shfl_xor(a4, 16, 64); a5 += __shfl_xor(a5, 16, 64);
  a6 += __shfl_xor(a6, 16, 64); a7 += __shfl_xor(a7, 16, 64);
  b0 += __shfl_xor(b0, 16, 64); b1 += __shfl_xor(b1, 16, 64);
  b2 += __shfl_xor(b2, 16, 64); b3 += __shfl_xor(b3, 16, 64);
  b4 += __shfl_xor(b4, 16, 64); b5 += __shfl_xor(b5, 16, 64);
  b6 += __shfl_xor(b6, 16, 64); b7 += __shfl_xor(b7, 16, 64);
  a0 += __shfl_xor(a0, 32, 64); a1 += __shfl_xor(a1, 32, 64);
  a2 += __shfl_xor(a2, 32, 64); a3 += __shfl_xor(a3, 32, 64);
  a4 += __shfl_xor(a4, 32, 64); a5 += __shfl_xor(a5, 32, 64);
  a6 += __shfl_xor(a6, 32, 64); a7 += __shfl_xor(a7, 32, 64);
  b0 += __shfl_xor(b0, 32, 64); b1 += __shfl_xor(b1, 32, 64);
  b2 += __shfl_xor(b2, 32, 64); b3 += __shfl_xor(b3, 32, 64);
  b4 += __shfl_xor(b4, 32, 64); b5 += __shfl_xor(b5, 32, 64);
  b6 += __shfl_xor(b6, 32, 64); b7 += __shfl_xor(b7, 32, 64);

  if (g == 0){
    uint4 rA, rB;
    rA.x = pack2(a0 + bfLo(selfA.x), a1 + bfHi(selfA.x));
    rA.y = pack2(a2 + bfLo(selfA.y), a3 + bfHi(selfA.y));
    rA.z = pack2(a4 + bfLo(selfA.z), a5 + bfHi(selfA.z));
    rA.w = pack2(a6 + bfLo(selfA.w), a7 + bfHi(selfA.w));
    rB.x = pack2(b0 + bfLo(selfB.x), b1 + bfHi(selfB.x));
    rB.y = pack2(b2 + bfLo(selfB.y), b3 + bfHi(selfB.y));
    rB.z = pack2(b4 + bfLo(selfB.z), b5 + bfHi(selfB.z));
    rB.w = pack2(b6 + bfLo(selfB.w), b7 + bfHi(selfB.w));
    *(uint4*)(ob + (size_t)nA*128 + o*8) = rA;
    *(uint4*)(ob + (size_t)nB*128 + o*8) = rB;
  }
}

// ---------- GIN MLP on h0: out = relu(h0@W1 + b1)@W2 + b2, in-place on block-owned rows ----------
__global__ __launch_bounds__(256) void k_mlp(ushort16* __restrict__ hb,
                                             const ushort16* __restrict__ Wt1, const float* __restrict__ b1,
                                             const ushort16* __restrict__ Wt2, const float* __restrict__ b2){
  __shared__ __attribute__((aligned(16))) ushort16 sA[64 * LDA];
  __shared__ __attribute__((aligned(16))) ushort16 sW[128 * LDA];
  int t = threadIdx.x;
  int row0 = blockIdx.x * 64;

  int sr = t >> 4;            // 0..15
  int sc = (t & 15) * 8;      // 0,8,...,120

  #pragma unroll
  for (int it = 0; it < 4; ++it){
    int row = it*16 + sr;
    int g = row0 + row;
    uint4 o = {0u,0u,0u,0u};
    if (g < N_NODES) o = *(const uint4*)(hb + (size_t)g*128 + sc);
    *(uint4*)(sA + row*LDA + sc) = o;
  }
  #pragma unroll
  for (int it = 0; it < 8; ++it){
    int row = it*16 + sr;
    *(uint4*)(sW + row*LDA + sc) = *(const uint4*)(Wt1 + row*128 + sc);
  }
  __syncthreads();

  int wave = t >> 6, l = t & 63, m = l & 15, kg = l >> 4;
  fx4 acc[8];
  #pragma unroll
  for (int nt = 0; nt < 8; ++nt) acc[nt] = (fx4){0.f,0.f,0.f,0.f};

  const ushort16* aBase = sA + (wave*16 + m)*LDA + kg*8;
  const ushort16* bBase = sW + m*LDA + kg*8;

  // GEMM1
  #pragma unroll
  for (int kt = 0; kt < 4; ++kt){
    bf16x8 av = *(const bf16x8*)(aBase + kt*32);
    #pragma unroll
    for (int nt = 0; nt < 8; ++nt){
      bf16x8 bv = *(const bf16x8*)(bBase + nt*16*LDA + kt*32);
      acc[nt] = __builtin_amdgcn_mfma_f32_16x16x32_bf16(av, bv, acc[nt], 0, 0, 0);
    }
  }
  __syncthreads();

  // h = relu(acc + b1) -> sA (C-layout: col = m + 16*nt, row = kg*4 + r)
  #pragma unroll
  for (int nt = 0; nt < 8; ++nt){
    float bv = b1[nt*16 + m];
    #pragma unroll
    for (int r = 0; r < 4; ++r){
      float v = acc[nt][r] + bv;
      v = fmaxf(v, 0.f);
      sA[(wave*16 + kg*4 + r)*LDA + nt*16 + m] = f2bf(v);
    }
  }
  // stage sW = W2^T
  #pragma unroll
  for (int it = 0; it < 8; ++it){
    int row = it*16 + sr;
    *(uint4*)(sW + row*LDA + sc) = *(const uint4*)(Wt2 + row*128 + sc);
  }
  __syncthreads();

  #pragma unroll
  for (int nt = 0; nt < 8; ++nt) acc[nt] = (fx4){0.f,0.f,0.f,0.f};

  // GEMM2
  #pragma unroll
  for (int kt = 0; kt < 4; ++kt){
    bf16x8 av = *(const bf16x8*)(aBase + kt*32);
    #pragma unroll
    for (int nt = 0; nt < 8; ++nt){
      bf16x8 bv = *(const bf16x8*)(bBase + nt*16*LDA + kt*32);
      acc[nt] = __builtin_amdgcn_mfma_f32_16x16x32_bf16(av, bv, acc[nt], 0, 0, 0);
    }
  }

  // epilogue: out = acc + b2 -> hb (in-place, only rows this block owns)
  #pragma unroll
  for (int nt = 0; nt < 8; ++nt){
    float bv = b2[nt*16 + m];
    #pragma unroll
    for (int r = 0; r < 4; ++r){
      int g = row0 + wave*16 + kg*4 + r;
      if (g < N_NODES){
        float v = acc[nt][r] + bv;
        hb[(size_t)g*128 + nt*16 + m] = f2bf(v);
      }
    }
  }
}

// ---------- sum-pool per graph (batch sorted), atomic-free: one block per graph ----------
__device__ __forceinline__ int lower_bound_i(const int* __restrict__ a, int n, int key){
  int lo = 0, hi = n;
  while (lo < hi){ int mid = (lo + hi) >> 1; if (a[mid] < key) lo = mid + 1; else hi = mid; }
  return lo;
}

__global__ __launch_bounds__(1024) void k_pool(const ushort16* __restrict__ xb, const int* __restrict__ batch,
                                               float* __restrict__ out){
  int g = blockIdx.x;
  int start = lower_bound_i(batch, N_NODES, g);
  int end   = lower_bound_i(batch, N_NODES, g + 1);
  int t = threadIdx.x;
  int c = t & 127;
  int h = t >> 7;   // 0..7
  float acc = 0.f;
  for (int r = start + h; r < end; r += 8){
    uint32 u = (uint32)xb[(size_t)r*128 + c];
    acc += __builtin_bit_cast(float, (uint32)(u << 16));
  }
  __shared__ float red[1024];
  red[t] = acc; __syncthreads();
  if (t < 512) red[t] += red[t + 512];
  __syncthreads();
  if (t < 256) red[t] += red[t + 256];
  __syncthreads();
  if (t < 128) out[(size_t)g*128 + c] = red[t] + red[t + 128];
}

// ---------- launch ----------
extern "C" void kernel_launch(void* const* d_in, const int* in_sizes, int n_in,
                              void* d_out, int out_size, void* d_ws, size_t ws_size,
                              hipStream_t stream) {
  const float* x   = (const float*)d_in[0];
  const float* W1  = (const float*)d_in[1];
  const float* b1  = (const float*)d_in[2];
  const float* W2  = (const float*)d_in[3];
  const float* b2  = (const float*)d_in[4];
  const int*   ei  = (const int*)d_in[5];
  const int*   bat = (const int*)d_in[6];
  float* out = (float*)d_out;

  char* w = (char*)d_ws;
  auto carve = [&](size_t bytes) -> char* {
    char* p = w; w += (bytes + 255) & ~(size_t)255; return p;
  };
  ushort16* P    = (ushort16*)carve((size_t)(N_NODES+1) * DIM * 2);  // +1: zero pad row
  ushort16* Q    = (ushort16*)carve((size_t)(N_NODES+1) * DIM * 2);
  ushort16* WtA  = (ushort16*)carve(3 * 16384 * 2);
  ushort16* WtB  = (ushort16*)carve(3 * 16384 * 2);
  int2* rowmeta  = (int2*)carve((size_t)N_NODES * 8);
  int* colx      = (int*)carve((size_t)NBKT * BP * 4);   // 8.03 MB, fixed bucket regions
  int* bucketCursor = (int*)carve((NBKT + 1) * 4);
  // temp bucket regions alias Q: only live during CSR build (first 9.63 MB; Q pad row at 25.6 MB is safe)
  int* temp      = (int*)Q;

  // 10 dispatches, no memsets
  k_prep<<<6635, 256, 0, stream>>>(x, P, Q, W1, W2, WtA, WtB, bucketCursor);
  k_binA<<<(N_EDGES + 8191)/8192, 512, 0, stream>>>(ei, bucketCursor, temp);
  k_binB<<<NBKT, 512, 0, stream>>>(temp, bucketCursor, rowmeta, colx);

  const int aggGrid = (N_NODES/2) / 16;       // 16 waves/block, 2 nodes/wave -> 3125 blocks
  const int mlpGrid = (N_NODES + 63) / 64;    // 1563

  // layer 0: h0 = P + agg(P) -> Q; mlp in-place on Q
  k_agg<<<aggGrid, 1024, 0, stream>>>(P, Q, rowmeta, colx);
  k_mlp<<<mlpGrid, 256, 0, stream>>>(Q, WtA + 0*16384, b1 + 0*128, WtB + 0*16384, b2 + 0*128);
  // layer 1: h0 = Q + agg(Q) -> P; mlp in-place on P
  k_agg<<<aggGrid, 1024, 0, stream>>>(Q, P, rowmeta, colx);
  k_mlp<<<mlpGrid, 256, 0, stream>>>(P, WtA + 1*16384, b1 + 1*128, WtB + 1*16384, b2 + 1*128);
  // layer 2: h0 = P + agg(P) -> Q; mlp in-place on Q
  k_agg<<<aggGrid, 1024, 0, stream>>>(P, Q, rowmeta, colx);
  k_mlp<<<mlpGrid, 256, 0, stream>>>(Q, WtA + 2*16384, b1 + 2*128, WtB + 2*16384, b2 + 2*128);

  k_pool<<<N_GRAPHS, 1024, 0, stream>>>(Q, bat, out);
}